// Round 2
// baseline (976.132 us; speedup 1.0000x reference)
//
#include <hip/hip_runtime.h>
#include <hip/hip_bf16.h>
#include <cstdint>
#include <cstddef>

typedef __bf16 bf16_t;
typedef __bf16 bf16x4 __attribute__((ext_vector_type(4)));
typedef __bf16 bf16x8 __attribute__((ext_vector_type(8)));
typedef float f32x4 __attribute__((ext_vector_type(4)));

// Problem constants
#define D_EMB   4096
#define N_HEADS 32
#define HEAD_D  128
#define SEQ     64
#define NBATCH  32
#define MTOT    2048  // NBATCH*SEQ
#define MB      1048576ULL

// ---------------- fp32 -> bf16 convert (vectorized, 4 elems/thread) --------
__global__ __launch_bounds__(256) void cvt_f32_bf16(const float* __restrict__ s,
                                                    bf16_t* __restrict__ d, int n4) {
  const int i = blockIdx.x * 256 + threadIdx.x;
  if (i < n4) {
    const float4 v = ((const float4*)s)[i];
    bf16x4 o;
    o[0] = (bf16_t)v.x; o[1] = (bf16_t)v.y; o[2] = (bf16_t)v.z; o[3] = (bf16_t)v.w;
    ((bf16x4*)d)[i] = o;
  }
}

// ---------------- async global->LDS (16B per lane) ----------------
__device__ __forceinline__ void lds_async16(void* lds, const void* gp) {
  __builtin_amdgcn_global_load_lds(
      (const __attribute__((address_space(1))) void*)gp,
      (__attribute__((address_space(3))) void*)lds, 16, 0, 0);
}

// ---------------- m97-style bt-GEMM core: C[128x128] tile ----------------
// A: MxK row-major bf16, B: NxK row-major bf16 (computes A @ B^T), BK=32.
// 256 threads = 4 waves; each wave owns a 64x64 subtile as 4x4 frags of
// mfma_f32_16x16x32_bf16.
__device__ __forceinline__ void gemm_core_bt(const bf16_t* __restrict__ A,
                                             const bf16_t* __restrict__ B,
                                             int K, int m0, int n0,
                                             bf16_t* As, bf16_t* Bs,
                                             f32x4 acc[4][4]) {
  const int tid  = threadIdx.x;
  const int lane = tid & 63;
  const int wave = tid >> 6;
  const int quad = lane >> 4;
  const int l16  = lane & 15;
  const int wm   = (wave >> 1) * 64;
  const int wn   = (wave & 1) * 64;

  // staging: 128 rows x 32 cols bf16 = 8KB = 512 x 16B chunks; 2/thread/tile
  const int q0 = tid;
  const int q1 = tid + 256;
  const int r0 = q0 >> 2, c0 = (q0 & 3) * 8;
  const int r1 = q1 >> 2, c1 = (q1 & 3) * 8;

  const bf16_t* Arow0 = A + (size_t)(m0 + r0) * K + c0;
  const bf16_t* Arow1 = A + (size_t)(m0 + r1) * K + c1;
  const bf16_t* Brow0 = B + (size_t)(n0 + r0) * K + c0;
  const bf16_t* Brow1 = B + (size_t)(n0 + r1) * K + c1;

  for (int k0 = 0; k0 < K; k0 += 32) {
    lds_async16(As + q0 * 8, Arow0 + k0);
    lds_async16(As + q1 * 8, Arow1 + k0);
    lds_async16(Bs + q0 * 8, Brow0 + k0);
    lds_async16(Bs + q1 * 8, Brow1 + k0);
    __syncthreads();  // compiler drains vmcnt before s_barrier

    bf16x8 af[4], bfv[4];
#pragma unroll
    for (int i = 0; i < 4; i++)
      af[i] = *(const bf16x8*)&As[(wm + 16 * i + l16) * 32 + quad * 8];
#pragma unroll
    for (int j = 0; j < 4; j++)
      bfv[j] = *(const bf16x8*)&Bs[(wn + 16 * j + l16) * 32 + quad * 8];
#pragma unroll
    for (int i = 0; i < 4; i++)
#pragma unroll
      for (int j = 0; j < 4; j++)
        acc[i][j] = __builtin_amdgcn_mfma_f32_16x16x32_bf16(af[i], bfv[j],
                                                            acc[i][j], 0, 0, 0);
    __syncthreads();
  }
}

// ---------------- Stage 1: fused 4-way projection GEMM ----------------
// grid (16, 128): x = M blocks, y = 4 matrices x 32 N-blocks
__global__ __launch_bounds__(256) void proj_gemm(
    const bf16_t* __restrict__ x,
    const bf16_t* __restrict__ Wq, const float* __restrict__ bq,
    const bf16_t* __restrict__ Wk, const float* __restrict__ bk,
    const bf16_t* __restrict__ Wv, const float* __restrict__ bv,
    const bf16_t* __restrict__ Wd, const float* __restrict__ bd,
    bf16_t* __restrict__ Qp, bf16_t* __restrict__ Kp,
    bf16_t* __restrict__ Vp, float* __restrict__ Gp) {
  __shared__ __align__(16) bf16_t As[128 * 32];
  __shared__ __align__(16) bf16_t Bs[128 * 32];

  const int m0  = blockIdx.x * 128;
  const int nb  = blockIdx.y;
  const int mat = nb >> 5;
  const int n0  = (nb & 31) * 128;

  const bf16_t* B; const float* bias;
  if (mat == 0)      { B = Wq; bias = bq; }
  else if (mat == 1) { B = Wk; bias = bk; }
  else if (mat == 2) { B = Wv; bias = bv; }
  else               { B = Wd; bias = bd; }

  f32x4 acc[4][4];
  const f32x4 zero = {0.f, 0.f, 0.f, 0.f};
#pragma unroll
  for (int i = 0; i < 4; i++)
#pragma unroll
    for (int j = 0; j < 4; j++) acc[i][j] = zero;

  gemm_core_bt(x, B, D_EMB, m0, n0, As, Bs, acc);

  const int tid = threadIdx.x, lane = tid & 63, wave = tid >> 6;
  const int quad = lane >> 4, l16 = lane & 15;
  const int wm = (wave >> 1) * 64, wn = (wave & 1) * 64;

#pragma unroll
  for (int i = 0; i < 4; i++) {
#pragma unroll
    for (int j = 0; j < 4; j++) {
      const int col = n0 + wn + 16 * j + l16;
      const float bv_ = bias[col];
      const int rowb = m0 + wm + 16 * i + quad * 4;
#pragma unroll
      for (int r = 0; r < 4; r++) {
        const float v = acc[i][j][r] + bv_;
        const size_t off = (size_t)(rowb + r) * D_EMB + col;
        if (mat == 0)      Qp[off] = (bf16_t)v;
        else if (mat == 1) Kp[off] = (bf16_t)v;
        else if (mat == 2) Vp[off] = (bf16_t)v;
        else               Gp[off] = v;   // keep gamma logits fp32
      }
    }
  }
}

// ---------------- Stage 2: per-(b,h) RoPE + decay + attention ----------------
// grid 1024 = 32 batches x 32 heads, 256 threads
__global__ __launch_bounds__(256) void attn_kernel(
    const bf16_t* __restrict__ Qp, const bf16_t* __restrict__ Kp,
    const bf16_t* __restrict__ Vp, const float* __restrict__ Gp,
    const float* __restrict__ t, bf16_t* __restrict__ attn) {
  __shared__ __align__(16) char smem[65536];
  bf16_t* Qs  = (bf16_t*)smem;              // 16KB: rope(Q) [64][128]
  bf16_t* Ks  = (bf16_t*)(smem + 16384);    // 16KB: rope(K)
  bf16_t* Gs  = (bf16_t*)(smem + 32768);    // 16KB: gc (cumprod gamma)
  bf16_t* IGs = (bf16_t*)(smem + 49152);    // 16KB: 1/gc

  const int tid = threadIdx.x;
  const int b = blockIdx.x >> 5, h = blockIdx.x & 31;
  const size_t base = (size_t)(b * SEQ) * D_EMB + (size_t)h * HEAD_D;

  // --- Phase 1a: RoPE on Q and K ---
  // reference's (swapped) layout: angle(s,d) = t[d&63] * 10000^(-s/64)
  for (int idx = tid; idx < SEQ * HEAD_D; idx += 256) {
    const int s = idx >> 7, d = idx & 127;
    const float invf = __expf(-0.14391156831212787f * (float)s);  // ln(1e4)/64
    const float theta = t[d & 63] * invf;
    float sn, cs;
    __sincosf(theta, &sn, &cs);
    const size_t po = base + (size_t)s * D_EMB;
    {
      const float v = (float)Qp[po + d];
      const float o = (float)Qp[po + (d ^ 64)];
      const float rot = (d < 64) ? -o : o;
      Qs[idx] = (bf16_t)(v * cs + rot * sn);
    }
    {
      const float v = (float)Kp[po + d];
      const float o = (float)Kp[po + (d ^ 64)];
      const float rot = (d < 64) ? -o : o;
      Ks[idx] = (bf16_t)(v * cs + rot * sn);
    }
  }
  // --- Phase 1b: gamma = sigmoid, cumprod over s (one thread per channel) ---
  if (tid < HEAD_D) {
    const int d = tid;
    float run = 1.0f;
    for (int s = 0; s < SEQ; s++) {
      const float z = Gp[base + (size_t)s * D_EMB + d];
      const float g = 1.0f / (1.0f + __expf(-z));
      run *= g;
      Gs[s * HEAD_D + d]  = (bf16_t)run;
      IGs[s * HEAD_D + d] = (bf16_t)(1.0f / run);
    }
  }
  __syncthreads();

  // --- Phase 2: decayed[q][k] = (Q[q].K[k]) * mean_d(gc[q]/gc[k]) * (k<=q) ---
  const int q = tid >> 2;
  const int klo = (tid & 3) * 16;
  float sc[16], dd[16];
#pragma unroll
  for (int kk = 0; kk < 16; kk++) { sc[kk] = 0.f; dd[kk] = 0.f; }

  for (int d8 = 0; d8 < HEAD_D; d8 += 8) {
    const bf16x8 qv = *(const bf16x8*)&Qs[q * HEAD_D + d8];
    const bf16x8 gv = *(const bf16x8*)&Gs[q * HEAD_D + d8];
    float qf[8], gf[8];
#pragma unroll
    for (int e = 0; e < 8; e++) { qf[e] = (float)qv[e]; gf[e] = (float)gv[e]; }
#pragma unroll
    for (int kk = 0; kk < 16; kk++) {
      const int k = klo + kk;
      if (k > q) continue;
      const bf16x8 kv = *(const bf16x8*)&Ks[k * HEAD_D + d8];
      const bf16x8 iv = *(const bf16x8*)&IGs[k * HEAD_D + d8];
#pragma unroll
      for (int e = 0; e < 8; e++) {
        sc[kk] += qf[e] * (float)kv[e];
        dd[kk] += gf[e] * (float)iv[e];
      }
    }
  }
  float dcy[16];
#pragma unroll
  for (int kk = 0; kk < 16; kk++)
    dcy[kk] = (klo + kk <= q) ? sc[kk] * dd[kk] * 0.0078125f : 0.f;

  __syncthreads();  // all reads of Qs/Ks/Gs/IGs done

  // --- Phase 3: park decayed in LDS (over Gs/IGs), V in LDS (over Qs) ---
  float*  Dcy = (float*)(smem + 32768);  // [64][68] fp32, padded stride
  bf16_t* Vs  = (bf16_t*)smem;           // [64][128]
#pragma unroll
  for (int kk = 0; kk < 16; kk++) Dcy[q * 68 + klo + kk] = dcy[kk];
  for (int idx = tid; idx < SEQ * HEAD_D; idx += 256)
    Vs[idx] = Vp[base + (size_t)(idx >> 7) * D_EMB + (idx & 127)];
  __syncthreads();

  // --- Phase 4: out[q][d] = sum_{k<=q} decayed[q][k] * V[k][d] ---
  const int g = tid & 3, d0 = g * 32;
  const int qq = tid >> 2;
  float o[32];
#pragma unroll
  for (int j = 0; j < 32; j++) o[j] = 0.f;
  for (int k = 0; k <= qq; k++) {
    const float w = Dcy[qq * 68 + k];
#pragma unroll
    for (int j8 = 0; j8 < 32; j8 += 8) {
      const bf16x8 vv = *(const bf16x8*)&Vs[k * HEAD_D + d0 + j8];
#pragma unroll
      for (int e = 0; e < 8; e++) o[j8 + e] += w * (float)vv[e];
    }
  }
  const size_t obase = (size_t)(b * SEQ + qq) * D_EMB + (size_t)h * HEAD_D + d0;
#pragma unroll
  for (int j = 0; j < 32; j++) attn[obase + j] = (bf16_t)o[j];
}

// ---------------- Stage 3: output projection GEMM (fp32 out) ----------------
__global__ __launch_bounds__(256) void out_gemm(
    const bf16_t* __restrict__ A, const bf16_t* __restrict__ Wo,
    const float* __restrict__ bo, float* __restrict__ out) {
  __shared__ __align__(16) bf16_t As[128 * 32];
  __shared__ __align__(16) bf16_t Bs[128 * 32];

  const int m0 = blockIdx.x * 128;
  const int n0 = blockIdx.y * 128;

  f32x4 acc[4][4];
  const f32x4 zero = {0.f, 0.f, 0.f, 0.f};
#pragma unroll
  for (int i = 0; i < 4; i++)
#pragma unroll
    for (int j = 0; j < 4; j++) acc[i][j] = zero;

  gemm_core_bt(A, Wo, D_EMB, m0, n0, As, Bs, acc);

  const int tid = threadIdx.x, lane = tid & 63, wave = tid >> 6;
  const int quad = lane >> 4, l16 = lane & 15;
  const int wm = (wave >> 1) * 64, wn = (wave & 1) * 64;

#pragma unroll
  for (int i = 0; i < 4; i++) {
#pragma unroll
    for (int j = 0; j < 4; j++) {
      const int col = n0 + wn + 16 * j + l16;
      const float bv_ = bo[col];
      const int rowb = m0 + wm + 16 * i + quad * 4;
#pragma unroll
      for (int r = 0; r < 4; r++)
        out[(size_t)(rowb + r) * D_EMB + col] = acc[i][j][r] + bv_;
    }
  }
}

// ---------------- launch ----------------
extern "C" void kernel_launch(void* const* d_in, const int* in_sizes, int n_in,
                              void* d_out, int out_size, void* d_ws, size_t ws_size,
                              hipStream_t stream) {
  const float* x  = (const float*)d_in[0];
  const float* t  = (const float*)d_in[1];
  const float* Wq = (const float*)d_in[2];
  const float* bq = (const float*)d_in[3];
  const float* Wk = (const float*)d_in[4];
  const float* bk = (const float*)d_in[5];
  const float* Wv = (const float*)d_in[6];
  const float* bv = (const float*)d_in[7];
  const float* Wd = (const float*)d_in[8];
  const float* bd = (const float*)d_in[9];
  const float* Wo = (const float*)d_in[10];
  const float* bo = (const float*)d_in[11];

  char* ws = (char*)d_ws;
  // ws layout (MB): xb@0(16, reused by attn after stage1) | Wqb@16 Wkb@48
  // Wvb@80 Wdb@112 Wob@144 (32 each) | Qp@176 Kp@192 Vp@208 (bf16 16 each) |
  // Gp@224 (fp32 32) -> total 256MB
  bf16_t* xb   = (bf16_t*)(ws);
  bf16_t* Wqb  = (bf16_t*)(ws + 16 * MB);
  bf16_t* Wkb  = (bf16_t*)(ws + 48 * MB);
  bf16_t* Wvb  = (bf16_t*)(ws + 80 * MB);
  bf16_t* Wdb  = (bf16_t*)(ws + 112 * MB);
  bf16_t* Wob  = (bf16_t*)(ws + 144 * MB);
  bf16_t* Qp   = (bf16_t*)(ws + 176 * MB);
  bf16_t* Kp   = (bf16_t*)(ws + 192 * MB);
  bf16_t* Vp   = (bf16_t*)(ws + 208 * MB);
  float*  Gp   = (float*) (ws + 224 * MB);
  bf16_t* attn = (bf16_t*)(ws);  // aliases xb (dead after proj_gemm)

  const int n4x = MTOT * D_EMB / 4;      // 2,097,152
  const int n4w = D_EMB * D_EMB / 4;     // 4,194,304
  cvt_f32_bf16<<<n4x / 256, 256, 0, stream>>>(x,  xb,  n4x);
  cvt_f32_bf16<<<n4w / 256, 256, 0, stream>>>(Wq, Wqb, n4w);
  cvt_f32_bf16<<<n4w / 256, 256, 0, stream>>>(Wk, Wkb, n4w);
  cvt_f32_bf16<<<n4w / 256, 256, 0, stream>>>(Wv, Wvb, n4w);
  cvt_f32_bf16<<<n4w / 256, 256, 0, stream>>>(Wd, Wdb, n4w);
  cvt_f32_bf16<<<n4w / 256, 256, 0, stream>>>(Wo, Wob, n4w);

  proj_gemm<<<dim3(16, 128), 256, 0, stream>>>(xb, Wqb, bq, Wkb, bk, Wvb, bv,
                                               Wdb, bd, Qp, Kp, Vp, Gp);
  attn_kernel<<<dim3(1024), 256, 0, stream>>>(Qp, Kp, Vp, Gp, t, attn);
  out_gemm<<<dim3(16, 32), 256, 0, stream>>>(attn, Wob, bo, (float*)d_out);
}

// Round 3
// 831.654 us; speedup vs baseline: 1.1737x; 1.1737x over previous
//
#include <hip/hip_runtime.h>
#include <hip/hip_bf16.h>
#include <cstdint>
#include <cstddef>

typedef __bf16 bf16_t;
typedef __bf16 bf16x4 __attribute__((ext_vector_type(4)));
typedef __bf16 bf16x8 __attribute__((ext_vector_type(8)));
typedef float f32x4 __attribute__((ext_vector_type(4)));

#define D_EMB   4096
#define N_HEADS 32
#define HEAD_D  128
#define SEQ     64
#define NBATCH  32
#define MTOT    2048
#define MB      1048576ULL
#define N4X     2097152   // MTOT*D_EMB/4  (2^21)
#define N4W     4194304   // D_EMB*D_EMB/4 (2^22)

// ---------------- fused fp32 -> bf16 convert: x + 5 weights, one launch ----
__global__ __launch_bounds__(256) void cvt_all(
    const float* __restrict__ x,  const float* __restrict__ w0,
    const float* __restrict__ w1, const float* __restrict__ w2,
    const float* __restrict__ w3, const float* __restrict__ w4,
    bf16_t* __restrict__ xb, bf16_t* __restrict__ d0, bf16_t* __restrict__ d1,
    bf16_t* __restrict__ d2, bf16_t* __restrict__ d3, bf16_t* __restrict__ d4) {
  const int i = blockIdx.x * 256 + threadIdx.x;
  const float* s; bf16_t* d; int j;
  if (i < N4X) { s = x; d = xb; j = i; }
  else {
    const int r = i - N4X;
    const int wi = r >> 22;          // / N4W
    j = r & (N4W - 1);
    if (wi == 0)      { s = w0; d = d0; }
    else if (wi == 1) { s = w1; d = d1; }
    else if (wi == 2) { s = w2; d = d2; }
    else if (wi == 3) { s = w3; d = d3; }
    else              { s = w4; d = d4; }
  }
  const float4 v = ((const float4*)s)[j];
  bf16x4 o;
  o[0] = (bf16_t)v.x; o[1] = (bf16_t)v.y; o[2] = (bf16_t)v.z; o[3] = (bf16_t)v.w;
  ((bf16x4*)d)[j] = o;
}

// ---------------- async global->LDS (16B per lane) ----------------
__device__ __forceinline__ void lds_async16(void* lds, const void* gp) {
  __builtin_amdgcn_global_load_lds(
      (const __attribute__((address_space(1))) void*)gp,
      (__attribute__((address_space(3))) void*)lds, 16, 0, 0);
}

// ---------------- m97-style bt-GEMM core: C[128x128] tile ----------------
__device__ __forceinline__ void gemm_core_bt(const bf16_t* __restrict__ A,
                                             const bf16_t* __restrict__ B,
                                             int K, int m0, int n0,
                                             bf16_t* As, bf16_t* Bs,
                                             f32x4 acc[4][4]) {
  const int tid  = threadIdx.x;
  const int lane = tid & 63;
  const int wave = tid >> 6;
  const int quad = lane >> 4;
  const int l16  = lane & 15;
  const int wm   = (wave >> 1) * 64;
  const int wn   = (wave & 1) * 64;

  const int q0 = tid;
  const int q1 = tid + 256;
  const int r0 = q0 >> 2, c0 = (q0 & 3) * 8;
  const int r1 = q1 >> 2, c1 = (q1 & 3) * 8;

  const bf16_t* Arow0 = A + (size_t)(m0 + r0) * K + c0;
  const bf16_t* Arow1 = A + (size_t)(m0 + r1) * K + c1;
  const bf16_t* Brow0 = B + (size_t)(n0 + r0) * K + c0;
  const bf16_t* Brow1 = B + (size_t)(n0 + r1) * K + c1;

  for (int k0 = 0; k0 < K; k0 += 32) {
    lds_async16(As + q0 * 8, Arow0 + k0);
    lds_async16(As + q1 * 8, Arow1 + k0);
    lds_async16(Bs + q0 * 8, Brow0 + k0);
    lds_async16(Bs + q1 * 8, Brow1 + k0);
    __syncthreads();

    bf16x8 af[4], bfv[4];
#pragma unroll
    for (int i = 0; i < 4; i++)
      af[i] = *(const bf16x8*)&As[(wm + 16 * i + l16) * 32 + quad * 8];
#pragma unroll
    for (int j = 0; j < 4; j++)
      bfv[j] = *(const bf16x8*)&Bs[(wn + 16 * j + l16) * 32 + quad * 8];
#pragma unroll
    for (int i = 0; i < 4; i++)
#pragma unroll
      for (int j = 0; j < 4; j++)
        acc[i][j] = __builtin_amdgcn_mfma_f32_16x16x32_bf16(af[i], bfv[j],
                                                            acc[i][j], 0, 0, 0);
    __syncthreads();
  }
}

// ---------------- Stage 1: fused 4-way projection GEMM ----------------
// grid (16, 128); mat 3 (gamma) applies sigmoid in-epilogue, stores bf16.
__global__ __launch_bounds__(256) void proj_gemm(
    const bf16_t* __restrict__ x,
    const bf16_t* __restrict__ Wq, const float* __restrict__ bq,
    const bf16_t* __restrict__ Wk, const float* __restrict__ bk,
    const bf16_t* __restrict__ Wv, const float* __restrict__ bv,
    const bf16_t* __restrict__ Wd, const float* __restrict__ bd,
    bf16_t* __restrict__ Qp, bf16_t* __restrict__ Kp,
    bf16_t* __restrict__ Vp, bf16_t* __restrict__ Gp) {
  __shared__ __align__(16) bf16_t As[128 * 32];
  __shared__ __align__(16) bf16_t Bs[128 * 32];

  const int m0  = blockIdx.x * 128;
  const int nb  = blockIdx.y;
  const int mat = nb >> 5;
  const int n0  = (nb & 31) * 128;

  const bf16_t* B; const float* bias; bf16_t* dst;
  if (mat == 0)      { B = Wq; bias = bq; dst = Qp; }
  else if (mat == 1) { B = Wk; bias = bk; dst = Kp; }
  else if (mat == 2) { B = Wv; bias = bv; dst = Vp; }
  else               { B = Wd; bias = bd; dst = Gp; }

  f32x4 acc[4][4];
  const f32x4 zero = {0.f, 0.f, 0.f, 0.f};
#pragma unroll
  for (int i = 0; i < 4; i++)
#pragma unroll
    for (int j = 0; j < 4; j++) acc[i][j] = zero;

  gemm_core_bt(x, B, D_EMB, m0, n0, As, Bs, acc);

  const int tid = threadIdx.x, lane = tid & 63, wave = tid >> 6;
  const int quad = lane >> 4, l16 = lane & 15;
  const int wm = (wave >> 1) * 64, wn = (wave & 1) * 64;
  const bool is_g = (mat == 3);

#pragma unroll
  for (int i = 0; i < 4; i++) {
#pragma unroll
    for (int j = 0; j < 4; j++) {
      const int col = n0 + wn + 16 * j + l16;
      const float bv_ = bias[col];
      const int rowb = m0 + wm + 16 * i + quad * 4;
#pragma unroll
      for (int r = 0; r < 4; r++) {
        float v = acc[i][j][r] + bv_;
        if (is_g) v = 1.0f / (1.0f + __expf(-v));  // gamma = sigmoid
        dst[(size_t)(rowb + r) * D_EMB + col] = (bf16_t)v;
      }
    }
  }
}

// ---------------- Stage 2: per-(b,h) RoPE + decay + attention (MFMA) -------
// grid 1024 = 32 b x 32 h, 256 threads (4 waves). All GEMMs are 16x16x32
// bt-frags identical to gemm_core_bt conventions (verified by stages 1/3).
__global__ __launch_bounds__(256) void attn_kernel(
    const bf16_t* __restrict__ Qp, const bf16_t* __restrict__ Kp,
    const bf16_t* __restrict__ Vp, const bf16_t* __restrict__ Gp,
    const float* __restrict__ t, bf16_t* __restrict__ attn) {
  __shared__ __align__(16) char smem[65536];
  bf16_t* Qs  = (bf16_t*)smem;              // [64][128] rope(Q)
  bf16_t* Ks  = (bf16_t*)(smem + 16384);    // [64][128] rope(K)
  bf16_t* Gs  = (bf16_t*)(smem + 32768);    // [64][128] gc
  bf16_t* IGs = (bf16_t*)(smem + 49152);    // [64][128] 1/gc
  // phase-3 overlay (over Gs/IGs):
  bf16_t* Ps  = (bf16_t*)(smem + 32768);           // [64][72] decayed, bf16
  bf16_t* Vt  = (bf16_t*)(smem + 32768 + 9216);    // [128][72] V transposed

  const int tid = threadIdx.x;
  const int lane = tid & 63, wv = tid >> 6;
  const int quad = lane >> 4, l16 = lane & 15;
  const int b = blockIdx.x >> 5, h = blockIdx.x & 31;
  const size_t base = (size_t)(b * SEQ) * D_EMB + (size_t)h * HEAD_D;

  // --- Phase 1a: RoPE on Q and K (reference's swapped-axis convention):
  // angle(s,d) = t[d&63] * 10000^(-s/64)
  for (int idx = tid; idx < SEQ * HEAD_D; idx += 256) {
    const int s = idx >> 7, d = idx & 127;
    const float invf = __expf(-0.14391156831212787f * (float)s);
    const float theta = t[d & 63] * invf;
    float sn, cs;
    __sincosf(theta, &sn, &cs);
    const size_t po = base + (size_t)s * D_EMB;
    {
      const float v = (float)Qp[po + d];
      const float o = (float)Qp[po + (d ^ 64)];
      const float rot = (d < 64) ? -o : o;
      Qs[idx] = (bf16_t)(v * cs + rot * sn);
    }
    {
      const float v = (float)Kp[po + d];
      const float o = (float)Kp[po + (d ^ 64)];
      const float rot = (d < 64) ? -o : o;
      Ks[idx] = (bf16_t)(v * cs + rot * sn);
    }
  }
  // --- Phase 1b: cumprod of gamma over s (one thread per channel) ---
  if (tid < HEAD_D) {
    const int d = tid;
    float run = 1.0f;
    for (int s = 0; s < SEQ; s++) {
      run *= (float)Gp[base + (size_t)s * D_EMB + d];
      Gs[s * HEAD_D + d]  = (bf16_t)run;
      IGs[s * HEAD_D + d] = (bf16_t)(1.0f / run);
    }
  }
  __syncthreads();

  // --- Phase 2: S = Q K^T, DD = gc (1/gc)^T via MFMA. Wave wv owns q-rows
  // [16wv,16wv+16); 4 col-frags j cover k=0..63. K-loop over HEAD_D. ---
  f32x4 Sa[4], Da[4];
  const f32x4 zero = {0.f, 0.f, 0.f, 0.f};
#pragma unroll
  for (int j = 0; j < 4; j++) { Sa[j] = zero; Da[j] = zero; }

  for (int k0 = 0; k0 < HEAD_D; k0 += 32) {
    const bf16x8 aq = *(const bf16x8*)&Qs[(wv * 16 + l16) * HEAD_D + quad * 8 + k0];
    const bf16x8 ag = *(const bf16x8*)&Gs[(wv * 16 + l16) * HEAD_D + quad * 8 + k0];
#pragma unroll
    for (int j = 0; j < 4; j++) {
      const bf16x8 bk = *(const bf16x8*)&Ks [(16 * j + l16) * HEAD_D + quad * 8 + k0];
      const bf16x8 bg = *(const bf16x8*)&IGs[(16 * j + l16) * HEAD_D + quad * 8 + k0];
      Sa[j] = __builtin_amdgcn_mfma_f32_16x16x32_bf16(aq, bk, Sa[j], 0, 0, 0);
      Da[j] = __builtin_amdgcn_mfma_f32_16x16x32_bf16(ag, bg, Da[j], 0, 0, 0);
    }
  }
  __syncthreads();  // done reading Gs/IGs (overlay follows)

  // --- Phase 3: decayed -> Ps (bf16, stride 72); V -> Vt transposed ---
  // C/D layout: row = 16wv + quad*4 + r, col = 16j + l16.
#pragma unroll
  for (int j = 0; j < 4; j++) {
#pragma unroll
    for (int r = 0; r < 4; r++) {
      const int q = wv * 16 + quad * 4 + r;
      const int k = 16 * j + l16;
      const float v = (k <= q) ? Sa[j][r] * Da[j][r] * 0.0078125f : 0.0f;
      Ps[q * 72 + k] = (bf16_t)v;
    }
  }
  for (int idx = tid; idx < SEQ * HEAD_D; idx += 256) {
    const int s = idx >> 7, d = idx & 127;
    Vt[d * 72 + s] = Vp[base + (size_t)s * D_EMB + d];
  }
  __syncthreads();

  // --- Phase 4: out = P V  (M=64, N=128, K=64). Wave wv owns q-rows
  // [16wv,+16); 8 col-frags cover d=0..127. ---
  f32x4 oa[8];
#pragma unroll
  for (int j = 0; j < 8; j++) oa[j] = zero;
  for (int k0 = 0; k0 < SEQ; k0 += 32) {
    const bf16x8 ap = *(const bf16x8*)&Ps[(wv * 16 + l16) * 72 + quad * 8 + k0];
#pragma unroll
    for (int j = 0; j < 8; j++) {
      const bf16x8 bv = *(const bf16x8*)&Vt[(16 * j + l16) * 72 + quad * 8 + k0];
      oa[j] = __builtin_amdgcn_mfma_f32_16x16x32_bf16(ap, bv, oa[j], 0, 0, 0);
    }
  }
#pragma unroll
  for (int j = 0; j < 8; j++) {
#pragma unroll
    for (int r = 0; r < 4; r++) {
      const int q = wv * 16 + quad * 4 + r;
      attn[(size_t)(b * SEQ + q) * D_EMB + (size_t)h * HEAD_D + 16 * j + l16] =
          (bf16_t)oa[j][r];
    }
  }
}

// ---------------- Stage 3: output projection GEMM (fp32 out) ----------------
__global__ __launch_bounds__(256) void out_gemm(
    const bf16_t* __restrict__ A, const bf16_t* __restrict__ Wo,
    const float* __restrict__ bo, float* __restrict__ out) {
  __shared__ __align__(16) bf16_t As[128 * 32];
  __shared__ __align__(16) bf16_t Bs[128 * 32];

  const int m0 = blockIdx.x * 128;
  const int n0 = blockIdx.y * 128;

  f32x4 acc[4][4];
  const f32x4 zero = {0.f, 0.f, 0.f, 0.f};
#pragma unroll
  for (int i = 0; i < 4; i++)
#pragma unroll
    for (int j = 0; j < 4; j++) acc[i][j] = zero;

  gemm_core_bt(A, Wo, D_EMB, m0, n0, As, Bs, acc);

  const int tid = threadIdx.x, lane = tid & 63, wave = tid >> 6;
  const int quad = lane >> 4, l16 = lane & 15;
  const int wm = (wave >> 1) * 64, wn = (wave & 1) * 64;

#pragma unroll
  for (int i = 0; i < 4; i++) {
#pragma unroll
    for (int j = 0; j < 4; j++) {
      const int col = n0 + wn + 16 * j + l16;
      const float bv_ = bo[col];
      const int rowb = m0 + wm + 16 * i + quad * 4;
#pragma unroll
      for (int r = 0; r < 4; r++)
        out[(size_t)(rowb + r) * D_EMB + col] = acc[i][j][r] + bv_;
    }
  }
}

// ---------------- launch ----------------
extern "C" void kernel_launch(void* const* d_in, const int* in_sizes, int n_in,
                              void* d_out, int out_size, void* d_ws, size_t ws_size,
                              hipStream_t stream) {
  const float* x  = (const float*)d_in[0];
  const float* t  = (const float*)d_in[1];
  const float* Wq = (const float*)d_in[2];
  const float* bq = (const float*)d_in[3];
  const float* Wk = (const float*)d_in[4];
  const float* bk = (const float*)d_in[5];
  const float* Wv = (const float*)d_in[6];
  const float* bv = (const float*)d_in[7];
  const float* Wd = (const float*)d_in[8];
  const float* bd = (const float*)d_in[9];
  const float* Wo = (const float*)d_in[10];
  const float* bo = (const float*)d_in[11];

  char* ws = (char*)d_ws;
  // ws (MB): xb@0 (16, reused as attn out) | Wqb@16 Wkb@48 Wvb@80 Wdb@112
  // Wob@144 (32 each) | Qp@176 Kp@192 Vp@208 Gp@224 (bf16 16 each) = 240MB
  bf16_t* xb   = (bf16_t*)(ws);
  bf16_t* Wqb  = (bf16_t*)(ws + 16 * MB);
  bf16_t* Wkb  = (bf16_t*)(ws + 48 * MB);
  bf16_t* Wvb  = (bf16_t*)(ws + 80 * MB);
  bf16_t* Wdb  = (bf16_t*)(ws + 112 * MB);
  bf16_t* Wob  = (bf16_t*)(ws + 144 * MB);
  bf16_t* Qp   = (bf16_t*)(ws + 176 * MB);
  bf16_t* Kp   = (bf16_t*)(ws + 192 * MB);
  bf16_t* Vp   = (bf16_t*)(ws + 208 * MB);
  bf16_t* Gp   = (bf16_t*)(ws + 224 * MB);
  bf16_t* attn = (bf16_t*)(ws);  // aliases xb (dead after proj_gemm)

  const int nblk = (N4X + 5 * N4W) / 256;  // 90112
  cvt_all<<<nblk, 256, 0, stream>>>(x, Wq, Wk, Wv, Wd, Wo,
                                    xb, Wqb, Wkb, Wvb, Wdb, Wob);
  proj_gemm<<<dim3(16, 128), 256, 0, stream>>>(xb, Wqb, bq, Wkb, bk, Wvb, bv,
                                               Wdb, bd, Qp, Kp, Vp, Gp);
  attn_kernel<<<dim3(1024), 256, 0, stream>>>(Qp, Kp, Vp, Gp, t, attn);
  out_gemm<<<dim3(16, 32), 256, 0, stream>>>(attn, Wob, bo, (float*)d_out);
}